// Round 7
// baseline (64.263 us; speedup 1.0000x reference)
//
#include <hip/hip_runtime.h>

typedef unsigned long long ull;

#define L_LEN 61440
#define NBATCH 512
#define EMAX 128
#define RUNBUF 128          // structurally <=120 output runs, <=60 target
#define NWORDS 960          // L_LEN / 64
#define NPADW 1080          // padded: w -> w + (w>>3)
#define PADW(w) ((w) + ((w) >> 3))
#define IOU_THRESH 0.2f
#define LEN_THRESH 128
#define PADPK 0xF000F000u   // s=61440, e=61440 packed

// ws layout (bytes):
//   [0, 3.93MB)            bmo: ull[512*960]   (output bitmasks, as ushort[512*3840])
//   [3.93MB, 7.86MB)       bmt: ull[512*960]
//   [7.86MB, +6KB)         per_row: int[512*3]
#define BM_WORDS_PER_ROW 960
#define BM_USHORT_PER_ROW 3840
#define PER_ROW_OFF (2u * NBATCH * BM_WORDS_PER_ROW * 8u)

#define NTILES 30720        // 512*61440/1024
#define NWAVES 6144         // 1536 blocks x 4 waves; x5 tiles each = 30720

__device__ __forceinline__ unsigned int nib_ge(float4 v, float thr) {
    return ((v.x >= thr) ? 1u : 0u) | ((v.y >= thr) ? 2u : 0u) |
           ((v.z >= thr) ? 4u : 0u) | ((v.w >= thr) ? 8u : 0u);
}
__device__ __forceinline__ unsigned int nib_ne0(float4 v) {
    return ((v.x != 0.0f) ? 1u : 0u) | ((v.y != 0.0f) ? 2u : 0u) |
           ((v.z != 0.0f) ? 4u : 0u) | ((v.w != 0.0f) ? 8u : 0u);
}

__device__ __forceinline__ float iou_pk(unsigned int pk, int ms, int me, int ml) {
    int s = (int)(pk & 0xffffu), e = (int)(pk >> 16);
    int lo = me < e ? me : e;
    int hi = ms > s ? ms : s;
    int inter = lo - hi; if (inter < 0) inter = 0;
    int den = ml + (e - s) - inter; if (den < 1) den = 1;
    return (float)inter / (float)den;
}

// ---------- kernel 1: pure streaming mask build (lane-contiguous float4) ----------
// Wave-tile = 1024 elems/signal: 4 chunks of 256; lane l owns elems 4l..4l+3 of each
// chunk (each load instruction is a contiguous 1KB across the wave).
// Nibble -> u32 (o low16, t high16) -> OR across lane-group-of-4 (2 shfl_xor)
// -> select u[lane&3] -> one ds_bpermute to linear order -> 2 coalesced 2B stores.
__global__ __launch_bounds__(256, 6) void mask_kernel(
        const float* __restrict__ outp, const float* __restrict__ tgtp,
        unsigned short* __restrict__ bmo_g, unsigned short* __restrict__ bmt_g) {
    const int tid = threadIdx.x;
    const int lane = tid & 63;
    const int wid = tid >> 6;
    const int gwid = blockIdx.x * 4 + wid;          // 0..6143
    const int sh = (lane & 3) * 4;
    const int bperm_addr = ((lane & 15) << 4) | ((lane >> 4) << 2);  // 4*src_lane

    #pragma unroll 1
    for (int j = 0; j < 5; ++j) {
        const int t = gwid * 5 + j;                 // tile id 0..30719
        const float* po = outp + (size_t)t * 1024 + lane * 4;
        const float* pt = tgtp + (size_t)t * 1024 + lane * 4;
        float4 a0 = *(const float4*)(po);
        float4 a1 = *(const float4*)(po + 256);
        float4 a2 = *(const float4*)(po + 512);
        float4 a3 = *(const float4*)(po + 768);
        float4 b0 = *(const float4*)(pt);
        float4 b1 = *(const float4*)(pt + 256);
        float4 b2 = *(const float4*)(pt + 512);
        float4 b3 = *(const float4*)(pt + 768);

        unsigned int u0 = (nib_ge(a0, 0.5f) | (nib_ne0(b0) << 16)) << sh;
        unsigned int u1 = (nib_ge(a1, 0.5f) | (nib_ne0(b1) << 16)) << sh;
        unsigned int u2 = (nib_ge(a2, 0.5f) | (nib_ne0(b2) << 16)) << sh;
        unsigned int u3 = (nib_ge(a3, 0.5f) | (nib_ne0(b3) << 16)) << sh;

        // OR-merge within lane groups of 4 -> every lane in group holds the
        // full 16-bit (per signal) word for (chunk c, k = lane>>2)
        u0 |= (unsigned)__shfl_xor((int)u0, 1, 64);
        u1 |= (unsigned)__shfl_xor((int)u1, 1, 64);
        u2 |= (unsigned)__shfl_xor((int)u2, 1, 64);
        u3 |= (unsigned)__shfl_xor((int)u3, 1, 64);
        u0 |= (unsigned)__shfl_xor((int)u0, 2, 64);
        u1 |= (unsigned)__shfl_xor((int)u1, 2, 64);
        u2 |= (unsigned)__shfl_xor((int)u2, 2, 64);
        u3 |= (unsigned)__shfl_xor((int)u3, 2, 64);

        // keep u[lane&3]; then pull from lane 4*(l&15)+(l>>4) so that dest
        // lane l holds ushort index l of the tile (c = l>>4, k = l&15)
        unsigned int s01 = (lane & 1) ? u1 : u0;
        unsigned int s23 = (lane & 1) ? u3 : u2;
        unsigned int rk  = (lane & 2) ? s23 : s01;
        unsigned int r = (unsigned)__builtin_amdgcn_ds_bpermute(bperm_addr, (int)rk);

        bmo_g[t * 64 + lane] = (unsigned short)(r & 0xffffu);
        bmt_g[t * 64 + lane] = (unsigned short)(r >> 16);
    }
}

// ---------- kernel 2: per-row extraction + filter + matching (unchanged, verified) ----------
__global__ __launch_bounds__(512) void match_kernel(
        const ull* __restrict__ bmo_u, const ull* __restrict__ bmt_u,
        int* __restrict__ per_row) {
    __shared__ ull bm[2][NPADW];
    __shared__ int runs_s[2][RUNBUF], runs_e[2][RUNBUF];
    __shared__ int wtot_s[8], wtot_e[8];
    __shared__ __align__(16) unsigned int pse_o[EMAX], pse_t[EMAX];
    __shared__ int idxr[EMAX], idxc[EMAX];
    __shared__ __align__(16) unsigned int rowfl[EMAX], colfl[EMAX];
    __shared__ int n_out_s, n_tgt_s, ftot0, tp_sh;

    const int tid = threadIdx.x;
    const int lane = tid & 63;
    const int wid = tid >> 6;
    const int row = blockIdx.x;

    if (tid == 0) tp_sh = 0;

    const int g = tid >> 8;            // 0 = output, 1 = target
    const int gtid = tid & 255;
    const int w0 = gtid * 4;
    const bool act = (gtid < 240);
    const ull* bsrc = (g == 0 ? bmo_u : bmt_u) + (size_t)row * BM_WORDS_PER_ROW;

    ull a = 0, b = 0, c = 0, dd = 0;
    if (act) {
        a = bsrc[w0]; b = bsrc[w0 + 1]; c = bsrc[w0 + 2]; dd = bsrc[w0 + 3];
        int p0 = PADW(w0);
        bm[g][p0] = a; bm[g][p0 + 1] = b; bm[g][p0 + 2] = c; bm[g][p0 + 3] = dd;
    }
    __syncthreads();

    ull swm0 = 0, swm1 = 0, swm2 = 0, swm3 = 0;
    ull ewm0 = 0, ewm1 = 0, ewm2 = 0, ewm3 = 0;
    int cs = 0, ce = 0;
    if (act) {
        ull wm1 = (w0 > 0) ? bm[g][PADW(w0 - 1)] : 0ull;
        ull wp4 = (w0 + 4 < NWORDS) ? bm[g][PADW(w0 + 4)] : 0ull;
        swm0 = a & ~((a << 1) | (wm1 >> 63)); ewm0 = a & ~((a >> 1) | (b << 63));
        swm1 = b & ~((b << 1) | (a >> 63));   ewm1 = b & ~((b >> 1) | (c << 63));
        swm2 = c & ~((c << 1) | (b >> 63));   ewm2 = c & ~((c >> 1) | (dd << 63));
        swm3 = dd & ~((dd << 1) | (c >> 63)); ewm3 = dd & ~((dd >> 1) | (wp4 << 63));
        cs = __popcll(swm0) + __popcll(swm1) + __popcll(swm2) + __popcll(swm3);
        ce = __popcll(ewm0) + __popcll(ewm1) + __popcll(ewm2) + __popcll(ewm3);
    }
    int incl_s = cs, incl_e = ce;
    #pragma unroll
    for (int d = 1; d < 64; d <<= 1) {
        int us = __shfl_up(incl_s, d, 64);
        int ue = __shfl_up(incl_e, d, 64);
        if (lane >= d) { incl_s += us; incl_e += ue; }
    }
    if (lane == 63) { wtot_s[wid] = incl_s; wtot_e[wid] = incl_e; }
    __syncthreads();
    int off_s = incl_s - cs, off_e = incl_e - ce;
    if (act) {
        for (int wv = (g << 2); wv < wid; ++wv) { off_s += wtot_s[wv]; off_e += wtot_e[wv]; }
        ull m; int base;
        m = swm0; base = w0 * 64;
        while (m) { int z = __builtin_ctzll(m); if (off_s < RUNBUF) runs_s[g][off_s] = base + z; ++off_s; m &= m - 1; }
        m = swm1; base += 64;
        while (m) { int z = __builtin_ctzll(m); if (off_s < RUNBUF) runs_s[g][off_s] = base + z; ++off_s; m &= m - 1; }
        m = swm2; base += 64;
        while (m) { int z = __builtin_ctzll(m); if (off_s < RUNBUF) runs_s[g][off_s] = base + z; ++off_s; m &= m - 1; }
        m = swm3; base += 64;
        while (m) { int z = __builtin_ctzll(m); if (off_s < RUNBUF) runs_s[g][off_s] = base + z; ++off_s; m &= m - 1; }
        m = ewm0; base = w0 * 64;
        while (m) { int z = __builtin_ctzll(m); if (off_e < RUNBUF) runs_e[g][off_e] = base + z + 1; ++off_e; m &= m - 1; }
        m = ewm1; base += 64;
        while (m) { int z = __builtin_ctzll(m); if (off_e < RUNBUF) runs_e[g][off_e] = base + z + 1; ++off_e; m &= m - 1; }
        m = ewm2; base += 64;
        while (m) { int z = __builtin_ctzll(m); if (off_e < RUNBUF) runs_e[g][off_e] = base + z + 1; ++off_e; m &= m - 1; }
        m = ewm3; base += 64;
        while (m) { int z = __builtin_ctzll(m); if (off_e < RUNBUF) runs_e[g][off_e] = base + z + 1; ++off_e; m &= m - 1; }
    }
    __syncthreads();

    const int nro = wtot_s[0] + wtot_s[1] + wtot_s[2] + wtot_s[3];
    const int nrt = wtot_s[4] + wtot_s[5] + wtot_s[6] + wtot_s[7];

    int keep = 0, fs = 0, fe = 0, fincl = 0;
    if (tid < 128) {
        int lim = nro < RUNBUF ? nro : RUNBUF;
        if (tid < lim) { fs = runs_s[0][tid]; fe = runs_e[0][tid]; keep = (fe - fs) >= LEN_THRESH ? 1 : 0; }
        fincl = keep;
        #pragma unroll
        for (int d = 1; d < 64; d <<= 1) {
            int u = __shfl_up(fincl, d, 64);
            if (lane >= d) fincl += u;
        }
        if (tid == 63) ftot0 = fincl;
    } else if (tid < 256) {
        int k = tid - 128;
        int mc = nrt < EMAX ? nrt : EMAX;
        pse_t[k] = (k < mc) ? ((unsigned)runs_s[1][k] | ((unsigned)runs_e[1][k] << 16)) : PADPK;
        if (k == 0) n_tgt_s = nrt;
    }
    __syncthreads();
    if (tid < 128) {
        int off = fincl - keep + (tid >= 64 ? ftot0 : 0);
        if (keep && off < EMAX) pse_o[off] = (unsigned)fs | ((unsigned)fe << 16);
        if (tid == 127) n_out_s = ftot0 + fincl;
    }
    __syncthreads();
    {
        int mcl = n_out_s < EMAX ? n_out_s : EMAX;
        if (tid < 128 && tid >= mcl) pse_o[tid] = PADPK;
    }
    __syncthreads();

    int ntc = n_tgt_s < EMAX ? n_tgt_s : EMAX;
    int noc = n_out_s < EMAX ? n_out_s : EMAX;
    const int nt4 = (ntc + 3) & ~3;
    const int no4 = (noc + 3) & ~3;

    unsigned mypk = PADPK;
    if (tid < 128) mypk = pse_o[tid];
    else if (tid < 256) mypk = pse_t[tid - 128];
    const int my_s = (int)(mypk & 0xffffu);
    const int my_e = (int)(mypk >> 16);
    const int my_len = my_e - my_s;

    // pass 0
    float best = -2.0f; int bi = 0;
    if (tid < 128) {
        for (int j = 0; j < nt4; j += 4) {
            uint4 pk = *(const uint4*)&pse_t[j];
            float v0 = iou_pk(pk.x, my_s, my_e, my_len);
            float v1 = iou_pk(pk.y, my_s, my_e, my_len);
            float v2 = iou_pk(pk.z, my_s, my_e, my_len);
            float v3 = iou_pk(pk.w, my_s, my_e, my_len);
            if (v0 > best) { best = v0; bi = j; }
            if (v1 > best) { best = v1; bi = j + 1; }
            if (v2 > best) { best = v2; bi = j + 2; }
            if (v3 > best) { best = v3; bi = j + 3; }
        }
        idxr[tid] = bi;
    } else if (tid < 256) {
        for (int i = 0; i < no4; i += 4) {
            uint4 pk = *(const uint4*)&pse_o[i];
            float v0 = iou_pk(pk.x, my_s, my_e, my_len);
            float v1 = iou_pk(pk.y, my_s, my_e, my_len);
            float v2 = iou_pk(pk.z, my_s, my_e, my_len);
            float v3 = iou_pk(pk.w, my_s, my_e, my_len);
            if (v0 > best) { best = v0; bi = i; }
            if (v1 > best) { best = v1; bi = i + 1; }
            if (v2 > best) { best = v2; bi = i + 2; }
            if (v3 > best) { best = v3; bi = i + 3; }
        }
        idxc[tid - 128] = bi;
    }
    __syncthreads();

    bool mm = false;
    if (tid < 128) mm = (idxc[bi] == tid) && (best >= IOU_THRESH);
    else if (tid < 256) mm = (idxr[bi] == tid - 128) && (best >= IOU_THRESH);
    if (tid < 128) {
        ull bb = __ballot(mm);
        if (lane == 0) atomicAdd(&tp_sh, (int)__popcll(bb));
    }
    __syncthreads();

    const int bi0 = bi;
    const bool m0 = mm;
    const bool one0 = (!mm) && (best >= IOU_THRESH);
    if (tid < 128)      rowfl[tid] = (unsigned)bi0 | (one0 ? 0x100u : 0u) | (m0 ? 0x200u : 0u);
    else if (tid < 256) colfl[tid - 128] = (unsigned)bi0 | (one0 ? 0x100u : 0u) | (m0 ? 0x200u : 0u);
    __syncthreads();

    // pass 1
    best = -2.0f; bi = 0;
    if (tid < 128) {
        const int i = tid;
        for (int j = 0; j < nt4; j += 4) {
            uint4 pk = *(const uint4*)&pse_t[j];
            uint4 fl = *(const uint4*)&colfl[j];
            bool om0 = (((j + 0 == bi0) && one0) || ((i == (int)(fl.x & 0xffu)) && (fl.x & 0x100u))) && !m0 && !(fl.x & 0x200u);
            bool om1 = (((j + 1 == bi0) && one0) || ((i == (int)(fl.y & 0xffu)) && (fl.y & 0x100u))) && !m0 && !(fl.y & 0x200u);
            bool om2 = (((j + 2 == bi0) && one0) || ((i == (int)(fl.z & 0xffu)) && (fl.z & 0x100u))) && !m0 && !(fl.z & 0x200u);
            bool om3 = (((j + 3 == bi0) && one0) || ((i == (int)(fl.w & 0xffu)) && (fl.w & 0x100u))) && !m0 && !(fl.w & 0x200u);
            float v0 = om0 ? iou_pk(pk.x, my_s, my_e, my_len) : -1.0f;
            float v1 = om1 ? iou_pk(pk.y, my_s, my_e, my_len) : -1.0f;
            float v2 = om2 ? iou_pk(pk.z, my_s, my_e, my_len) : -1.0f;
            float v3 = om3 ? iou_pk(pk.w, my_s, my_e, my_len) : -1.0f;
            if (v0 > best) { best = v0; bi = j; }
            if (v1 > best) { best = v1; bi = j + 1; }
            if (v2 > best) { best = v2; bi = j + 2; }
            if (v3 > best) { best = v3; bi = j + 3; }
        }
        idxr[tid] = bi;
    } else if (tid < 256) {
        const int j = tid - 128;
        for (int i = 0; i < no4; i += 4) {
            uint4 pk = *(const uint4*)&pse_o[i];
            uint4 fl = *(const uint4*)&rowfl[i];
            bool om0 = (((j == (int)(fl.x & 0xffu)) && (fl.x & 0x100u)) || ((i + 0 == bi0) && one0)) && !(fl.x & 0x200u) && !m0;
            bool om1 = (((j == (int)(fl.y & 0xffu)) && (fl.y & 0x100u)) || ((i + 1 == bi0) && one0)) && !(fl.y & 0x200u) && !m0;
            bool om2 = (((j == (int)(fl.z & 0xffu)) && (fl.z & 0x100u)) || ((i + 2 == bi0) && one0)) && !(fl.z & 0x200u) && !m0;
            bool om3 = (((j == (int)(fl.w & 0xffu)) && (fl.w & 0x100u)) || ((i + 3 == bi0) && one0)) && !(fl.w & 0x200u) && !m0;
            float v0 = om0 ? iou_pk(pk.x, my_s, my_e, my_len) : -1.0f;
            float v1 = om1 ? iou_pk(pk.y, my_s, my_e, my_len) : -1.0f;
            float v2 = om2 ? iou_pk(pk.z, my_s, my_e, my_len) : -1.0f;
            float v3 = om3 ? iou_pk(pk.w, my_s, my_e, my_len) : -1.0f;
            if (v0 > best) { best = v0; bi = i; }
            if (v1 > best) { best = v1; bi = i + 1; }
            if (v2 > best) { best = v2; bi = i + 2; }
            if (v3 > best) { best = v3; bi = i + 3; }
        }
        idxc[tid - 128] = bi;
    }
    __syncthreads();

    mm = false;
    if (tid < 128) mm = (idxc[bi] == tid) && (best >= IOU_THRESH);
    else if (tid < 256) mm = (idxr[bi] == tid - 128) && (best >= IOU_THRESH);
    if (tid < 128) {
        ull bb = __ballot(mm);
        if (lane == 0) atomicAdd(&tp_sh, (int)__popcll(bb));
    }
    __syncthreads();

    if (tid == 0) {
        int n_out = n_out_s, n_tgt = n_tgt_s, tp = tp_sh;
        int tpb, fnb, fpb;
        if (n_tgt == 0)      { tpb = 0;  fnb = n_out;      fpb = 0; }
        else if (n_out == 0) { tpb = 0;  fnb = 0;          fpb = n_tgt; }
        else                 { tpb = tp; fnb = n_tgt - tp; fpb = n_out - tp; }
        per_row[row * 3 + 0] = tpb;
        per_row[row * 3 + 1] = fnb;
        per_row[row * 3 + 2] = fpb;
    }
}

__global__ __launch_bounds__(512) void finalize_kernel(const int* __restrict__ per_row,
                                                       float* __restrict__ out) {
    __shared__ int sm[3][8];
    const int tid = threadIdx.x;
    const int lane = tid & 63;
    const int wid = tid >> 6;
    int tp = per_row[tid * 3 + 0];
    int fn = per_row[tid * 3 + 1];
    int fp = per_row[tid * 3 + 2];
    #pragma unroll
    for (int d = 32; d > 0; d >>= 1) {
        tp += __shfl_down(tp, d, 64);
        fn += __shfl_down(fn, d, 64);
        fp += __shfl_down(fp, d, 64);
    }
    if (lane == 0) { sm[0][wid] = tp; sm[1][wid] = fn; sm[2][wid] = fp; }
    __syncthreads();
    if (tid == 0) {
        int TPi = 0, FNi = 0, FPi = 0;
        #pragma unroll
        for (int w = 0; w < 8; ++w) { TPi += sm[0][w]; FNi += sm[1][w]; FPi += sm[2][w]; }
        float TP = (float)TPi, FN = (float)FNi, FP = (float)FPi;
        float rd = TP + FN;
        float recall = (rd == 0.0f) ? 0.0f : TP / fmaxf(rd, 1.0f);
        float pd = TP + FP;
        float precision = (pd == 0.0f) ? 0.0f : TP / fmaxf(pd, 1.0f);
        float s = precision + recall;
        float f1 = (s == 0.0f) ? 0.0f : 2.0f * precision * recall / fmaxf(s, 1e-30f);
        out[0] = recall; out[1] = precision; out[2] = f1;
    }
}

extern "C" void kernel_launch(void* const* d_in, const int* in_sizes, int n_in,
                              void* d_out, int out_size, void* d_ws, size_t ws_size,
                              hipStream_t stream) {
    const float* outp = (const float*)d_in[0];
    const float* tgtp = (const float*)d_in[1];
    float* res = (float*)d_out;

    char* ws = (char*)d_ws;
    unsigned short* bmo_g = (unsigned short*)ws;
    unsigned short* bmt_g = (unsigned short*)(ws + (size_t)NBATCH * BM_WORDS_PER_ROW * 8);
    int* per_row = (int*)(ws + PER_ROW_OFF);

    mask_kernel<<<NWAVES / 4, 256, 0, stream>>>(outp, tgtp, bmo_g, bmt_g);
    match_kernel<<<NBATCH, 512, 0, stream>>>((const ull*)bmo_g, (const ull*)bmt_g, per_row);
    finalize_kernel<<<1, 512, 0, stream>>>(per_row, res);
}

// Round 8
// 55.986 us; speedup vs baseline: 1.1478x; 1.1478x over previous
//
#include <hip/hip_runtime.h>

typedef unsigned long long ull;

#define L_LEN 61440
#define NBATCH 512
#define EMAX 128
#define RUNBUF 128          // structurally <=120 output runs, <=60 target
#define NWORDS 960          // L_LEN / 64
#define NPADW 1080          // padded: w -> w + (w>>3)
#define PADW(w) ((w) + ((w) >> 3))
#define NTHREADS 768
#define IOU_THRESH 0.2f
#define LEN_THRESH 128
#define PADPK 0xF000F000u   // s=61440, e=61440 packed

__device__ __forceinline__ unsigned int mask16_ge(float4 a, float4 b, float4 c, float4 d, float thr) {
    unsigned int m = 0;
    m |= (a.x >= thr) ? 0x0001u : 0u; m |= (a.y >= thr) ? 0x0002u : 0u;
    m |= (a.z >= thr) ? 0x0004u : 0u; m |= (a.w >= thr) ? 0x0008u : 0u;
    m |= (b.x >= thr) ? 0x0010u : 0u; m |= (b.y >= thr) ? 0x0020u : 0u;
    m |= (b.z >= thr) ? 0x0040u : 0u; m |= (b.w >= thr) ? 0x0080u : 0u;
    m |= (c.x >= thr) ? 0x0100u : 0u; m |= (c.y >= thr) ? 0x0200u : 0u;
    m |= (c.z >= thr) ? 0x0400u : 0u; m |= (c.w >= thr) ? 0x0800u : 0u;
    m |= (d.x >= thr) ? 0x1000u : 0u; m |= (d.y >= thr) ? 0x2000u : 0u;
    m |= (d.z >= thr) ? 0x4000u : 0u; m |= (d.w >= thr) ? 0x8000u : 0u;
    return m;
}

__device__ __forceinline__ unsigned int mask16_ne0(float4 a, float4 b, float4 c, float4 d) {
    unsigned int m = 0;
    m |= (a.x != 0.0f) ? 0x0001u : 0u; m |= (a.y != 0.0f) ? 0x0002u : 0u;
    m |= (a.z != 0.0f) ? 0x0004u : 0u; m |= (a.w != 0.0f) ? 0x0008u : 0u;
    m |= (b.x != 0.0f) ? 0x0010u : 0u; m |= (b.y != 0.0f) ? 0x0020u : 0u;
    m |= (b.z != 0.0f) ? 0x0040u : 0u; m |= (b.w != 0.0f) ? 0x0080u : 0u;
    m |= (c.x != 0.0f) ? 0x0100u : 0u; m |= (c.y != 0.0f) ? 0x0200u : 0u;
    m |= (c.z != 0.0f) ? 0x0400u : 0u; m |= (c.w != 0.0f) ? 0x0800u : 0u;
    m |= (d.x != 0.0f) ? 0x1000u : 0u; m |= (d.y != 0.0f) ? 0x2000u : 0u;
    m |= (d.z != 0.0f) ? 0x4000u : 0u; m |= (d.w != 0.0f) ? 0x8000u : 0u;
    return m;
}

__device__ __forceinline__ float iou_pk(unsigned int pk, int ms, int me, int ml) {
    int s = (int)(pk & 0xffffu), e = (int)(pk >> 16);
    int lo = me < e ? me : e;
    int hi = ms > s ? ms : s;
    int inter = lo - hi; if (inter < 0) inter = 0;
    int den = ml + (e - s) - inter; if (den < 1) den = 1;
    return (float)inter / (float)den;
}

// depth-2 software-pipelined load phase: 8 loads of iteration k+1 are issued
// BEFORE the masks of iteration k are computed -> compiler emits vmcnt(8)
// instead of vmcnt(0): one full batch always in flight through the ALU/store window.
#define LOAD8(A0,A1,A2,A3,B0,B1,B2,B3, IT) { \
    const float4* po_ = (const float4*)(op + (IT) * 12288 + tid * 16); \
    const float4* pt_ = (const float4*)(tg + (IT) * 12288 + tid * 16); \
    A0 = po_[0]; A1 = po_[1]; A2 = po_[2]; A3 = po_[3]; \
    B0 = pt_[0]; B1 = pt_[1]; B2 = pt_[2]; B3 = pt_[3]; }

#define PROC(IT, A0,A1,A2,A3,B0,B1,B2,B3) { \
    unsigned int mo_ = mask16_ge(A0, A1, A2, A3, 0.5f); \
    unsigned int mt_ = mask16_ne0(B0, B1, B2, B3); \
    unsigned int u_ = (IT) * NTHREADS + tid; \
    unsigned int pu_ = u_ + ((u_ >> 5) << 2); \
    bmo16[pu_] = (unsigned short)mo_; \
    bmt16[pu_] = (unsigned short)mt_; }

__global__ __launch_bounds__(NTHREADS, 6) void event_f1_kernel(
        const float* __restrict__ outp, const float* __restrict__ tgtp,
        int* __restrict__ per_row) {
    __shared__ ull bm[2][NPADW];                       // padded bitmask layout
    __shared__ int runs_s[2][RUNBUF], runs_e[2][RUNBUF];
    __shared__ int wtot_s[16], wtot_e[16];
    __shared__ __align__(16) unsigned int pse_o[EMAX], pse_t[EMAX];
    __shared__ int idxr[EMAX], idxc[EMAX];
    __shared__ __align__(16) unsigned int rowfl[EMAX], colfl[EMAX];
    __shared__ int n_out_s, n_tgt_s, ftot0, tp_sh;

    const int tid = threadIdx.x;
    const int lane = tid & 63;
    const int wid = tid >> 6;
    const int row = blockIdx.x;

    const float* op = outp + (size_t)row * L_LEN;
    const float* tg = tgtp + (size_t)row * L_LEN;

    if (tid == 0) tp_sh = 0;

    // ---- 1) build both bitmasks: 768 thr x 16 elems x 5 iters = 61440 exact ----
    unsigned short* bmo16 = (unsigned short*)bm[0];
    unsigned short* bmt16 = (unsigned short*)bm[1];
    {
        float4 a0, a1, a2, a3, b0, b1, b2, b3;
        float4 c0, c1, c2, c3, d0, d1, d2, d3;
        LOAD8(a0, a1, a2, a3, b0, b1, b2, b3, 0);
        LOAD8(c0, c1, c2, c3, d0, d1, d2, d3, 1);
        PROC(0, a0, a1, a2, a3, b0, b1, b2, b3);
        LOAD8(a0, a1, a2, a3, b0, b1, b2, b3, 2);
        PROC(1, c0, c1, c2, c3, d0, d1, d2, d3);
        LOAD8(c0, c1, c2, c3, d0, d1, d2, d3, 3);
        PROC(2, a0, a1, a2, a3, b0, b1, b2, b3);
        LOAD8(a0, a1, a2, a3, b0, b1, b2, b3, 4);
        PROC(3, c0, c1, c2, c3, d0, d1, d2, d3);
        PROC(4, a0, a1, a2, a3, b0, b1, b2, b3);
    }
    __syncthreads();

    // ---- 2) run extraction: threads 0-255 -> output, 256-511 -> target ----
    const int group = tid >> 8;            // 0,1 active; 2 idle
    const int g = group & 1;
    const int gtid = tid & 255;
    const ull* bmp = bm[g];
    const int w0 = gtid * 4;
    const bool act = (tid < 512) && (gtid < 240);

    ull swm0 = 0, swm1 = 0, swm2 = 0, swm3 = 0;
    ull ewm0 = 0, ewm1 = 0, ewm2 = 0, ewm3 = 0;
    int cs = 0, ce = 0;
    if (act) {
        ull wm1 = (w0 > 0) ? bmp[PADW(w0 - 1)] : 0ull;
        int p0 = PADW(w0);
        ull a = bmp[p0], b = bmp[p0 + 1], c = bmp[p0 + 2], d = bmp[p0 + 3];
        ull wp4 = (w0 + 4 < NWORDS) ? bmp[PADW(w0 + 4)] : 0ull;
        swm0 = a & ~((a << 1) | (wm1 >> 63)); ewm0 = a & ~((a >> 1) | (b << 63));
        swm1 = b & ~((b << 1) | (a >> 63));   ewm1 = b & ~((b >> 1) | (c << 63));
        swm2 = c & ~((c << 1) | (b >> 63));   ewm2 = c & ~((c >> 1) | (d << 63));
        swm3 = d & ~((d << 1) | (c >> 63));   ewm3 = d & ~((d >> 1) | (wp4 << 63));
        cs = __popcll(swm0) + __popcll(swm1) + __popcll(swm2) + __popcll(swm3);
        ce = __popcll(ewm0) + __popcll(ewm1) + __popcll(ewm2) + __popcll(ewm3);
    }
    // wave inclusive scan
    int incl_s = cs, incl_e = ce;
    #pragma unroll
    for (int d = 1; d < 64; d <<= 1) {
        int us = __shfl_up(incl_s, d, 64);
        int ue = __shfl_up(incl_e, d, 64);
        if (lane >= d) { incl_s += us; incl_e += ue; }
    }
    if (lane == 63) { wtot_s[wid] = incl_s; wtot_e[wid] = incl_e; }
    __syncthreads();
    int off_s = incl_s - cs, off_e = incl_e - ce;
    if (act) {
        for (int wv = (g << 2); wv < wid; ++wv) { off_s += wtot_s[wv]; off_e += wtot_e[wv]; }
        ull m; int base;
        m = swm0; base = w0 * 64;
        while (m) { int z = __builtin_ctzll(m); if (off_s < RUNBUF) runs_s[g][off_s] = base + z; ++off_s; m &= m - 1; }
        m = swm1; base += 64;
        while (m) { int z = __builtin_ctzll(m); if (off_s < RUNBUF) runs_s[g][off_s] = base + z; ++off_s; m &= m - 1; }
        m = swm2; base += 64;
        while (m) { int z = __builtin_ctzll(m); if (off_s < RUNBUF) runs_s[g][off_s] = base + z; ++off_s; m &= m - 1; }
        m = swm3; base += 64;
        while (m) { int z = __builtin_ctzll(m); if (off_s < RUNBUF) runs_s[g][off_s] = base + z; ++off_s; m &= m - 1; }
        m = ewm0; base = w0 * 64;
        while (m) { int z = __builtin_ctzll(m); if (off_e < RUNBUF) runs_e[g][off_e] = base + z + 1; ++off_e; m &= m - 1; }
        m = ewm1; base += 64;
        while (m) { int z = __builtin_ctzll(m); if (off_e < RUNBUF) runs_e[g][off_e] = base + z + 1; ++off_e; m &= m - 1; }
        m = ewm2; base += 64;
        while (m) { int z = __builtin_ctzll(m); if (off_e < RUNBUF) runs_e[g][off_e] = base + z + 1; ++off_e; m &= m - 1; }
        m = ewm3; base += 64;
        while (m) { int z = __builtin_ctzll(m); if (off_e < RUNBUF) runs_e[g][off_e] = base + z + 1; ++off_e; m &= m - 1; }
    }
    __syncthreads();

    const int nro = wtot_s[0] + wtot_s[1] + wtot_s[2] + wtot_s[3];
    const int nrt = wtot_s[4] + wtot_s[5] + wtot_s[6] + wtot_s[7];

    // ---- 3) filter output runs (threads 0-127); copy target (128-255) ----
    int keep = 0, fs = 0, fe = 0, fincl = 0;
    if (tid < 128) {
        int lim = nro < RUNBUF ? nro : RUNBUF;
        if (tid < lim) { fs = runs_s[0][tid]; fe = runs_e[0][tid]; keep = (fe - fs) >= LEN_THRESH ? 1 : 0; }
        fincl = keep;
        #pragma unroll
        for (int d = 1; d < 64; d <<= 1) {
            int u = __shfl_up(fincl, d, 64);
            if (lane >= d) fincl += u;
        }
        if (tid == 63) ftot0 = fincl;
    } else if (tid < 256) {
        int k = tid - 128;
        int mc = nrt < EMAX ? nrt : EMAX;
        pse_t[k] = (k < mc) ? ((unsigned)runs_s[1][k] | ((unsigned)runs_e[1][k] << 16)) : PADPK;
        if (k == 0) n_tgt_s = nrt;
    }
    __syncthreads();
    if (tid < 128) {
        int off = fincl - keep + (tid >= 64 ? ftot0 : 0);
        if (keep && off < EMAX) pse_o[off] = (unsigned)fs | ((unsigned)fe << 16);
        if (tid == 127) n_out_s = ftot0 + fincl;
    }
    __syncthreads();
    {
        int mcl = n_out_s < EMAX ? n_out_s : EMAX;
        if (tid < 128 && tid >= mcl) pse_o[tid] = PADPK;
    }
    __syncthreads();

    // ---- 4) matching (threads 0-255; rows 0-127, cols 128-255) ----
    int ntc = n_tgt_s < EMAX ? n_tgt_s : EMAX;
    int noc = n_out_s < EMAX ? n_out_s : EMAX;
    const int nt4 = (ntc + 3) & ~3;
    const int no4 = (noc + 3) & ~3;

    unsigned mypk = PADPK;
    if (tid < 128) mypk = pse_o[tid];
    else if (tid < 256) mypk = pse_t[tid - 128];
    const int my_s = (int)(mypk & 0xffffu);
    const int my_e = (int)(mypk >> 16);
    const int my_len = my_e - my_s;

    // pass 0
    float best = -2.0f; int bi = 0;
    if (tid < 128) {
        for (int j = 0; j < nt4; j += 4) {
            uint4 pk = *(const uint4*)&pse_t[j];
            float v0 = iou_pk(pk.x, my_s, my_e, my_len);
            float v1 = iou_pk(pk.y, my_s, my_e, my_len);
            float v2 = iou_pk(pk.z, my_s, my_e, my_len);
            float v3 = iou_pk(pk.w, my_s, my_e, my_len);
            if (v0 > best) { best = v0; bi = j; }
            if (v1 > best) { best = v1; bi = j + 1; }
            if (v2 > best) { best = v2; bi = j + 2; }
            if (v3 > best) { best = v3; bi = j + 3; }
        }
        idxr[tid] = bi;
    } else if (tid < 256) {
        for (int i = 0; i < no4; i += 4) {
            uint4 pk = *(const uint4*)&pse_o[i];
            float v0 = iou_pk(pk.x, my_s, my_e, my_len);
            float v1 = iou_pk(pk.y, my_s, my_e, my_len);
            float v2 = iou_pk(pk.z, my_s, my_e, my_len);
            float v3 = iou_pk(pk.w, my_s, my_e, my_len);
            if (v0 > best) { best = v0; bi = i; }
            if (v1 > best) { best = v1; bi = i + 1; }
            if (v2 > best) { best = v2; bi = i + 2; }
            if (v3 > best) { best = v3; bi = i + 3; }
        }
        idxc[tid - 128] = bi;
    }
    __syncthreads();

    bool mm = false;
    if (tid < 128) mm = (idxc[bi] == tid) && (best >= IOU_THRESH);
    else if (tid < 256) mm = (idxr[bi] == tid - 128) && (best >= IOU_THRESH);
    if (tid < 128) {
        ull bb = __ballot(mm);
        if (lane == 0) atomicAdd(&tp_sh, (int)__popcll(bb));
    }
    __syncthreads();

    const int bi0 = bi;
    const bool m0 = mm;
    const bool one0 = (!mm) && (best >= IOU_THRESH);
    if (tid < 128)      rowfl[tid] = (unsigned)bi0 | (one0 ? 0x100u : 0u) | (m0 ? 0x200u : 0u);
    else if (tid < 256) colfl[tid - 128] = (unsigned)bi0 | (one0 ? 0x100u : 0u) | (m0 ? 0x200u : 0u);
    __syncthreads();

    // pass 1
    best = -2.0f; bi = 0;
    if (tid < 128) {
        const int i = tid;
        for (int j = 0; j < nt4; j += 4) {
            uint4 pk = *(const uint4*)&pse_t[j];
            uint4 fl = *(const uint4*)&colfl[j];
            bool om0 = (((j + 0 == bi0) && one0) || ((i == (int)(fl.x & 0xffu)) && (fl.x & 0x100u))) && !m0 && !(fl.x & 0x200u);
            bool om1 = (((j + 1 == bi0) && one0) || ((i == (int)(fl.y & 0xffu)) && (fl.y & 0x100u))) && !m0 && !(fl.y & 0x200u);
            bool om2 = (((j + 2 == bi0) && one0) || ((i == (int)(fl.z & 0xffu)) && (fl.z & 0x100u))) && !m0 && !(fl.z & 0x200u);
            bool om3 = (((j + 3 == bi0) && one0) || ((i == (int)(fl.w & 0xffu)) && (fl.w & 0x100u))) && !m0 && !(fl.w & 0x200u);
            float v0 = om0 ? iou_pk(pk.x, my_s, my_e, my_len) : -1.0f;
            float v1 = om1 ? iou_pk(pk.y, my_s, my_e, my_len) : -1.0f;
            float v2 = om2 ? iou_pk(pk.z, my_s, my_e, my_len) : -1.0f;
            float v3 = om3 ? iou_pk(pk.w, my_s, my_e, my_len) : -1.0f;
            if (v0 > best) { best = v0; bi = j; }
            if (v1 > best) { best = v1; bi = j + 1; }
            if (v2 > best) { best = v2; bi = j + 2; }
            if (v3 > best) { best = v3; bi = j + 3; }
        }
        idxr[tid] = bi;
    } else if (tid < 256) {
        const int j = tid - 128;
        for (int i = 0; i < no4; i += 4) {
            uint4 pk = *(const uint4*)&pse_o[i];
            uint4 fl = *(const uint4*)&rowfl[i];
            bool om0 = (((j == (int)(fl.x & 0xffu)) && (fl.x & 0x100u)) || ((i + 0 == bi0) && one0)) && !(fl.x & 0x200u) && !m0;
            bool om1 = (((j == (int)(fl.y & 0xffu)) && (fl.y & 0x100u)) || ((i + 1 == bi0) && one0)) && !(fl.y & 0x200u) && !m0;
            bool om2 = (((j == (int)(fl.z & 0xffu)) && (fl.z & 0x100u)) || ((i + 2 == bi0) && one0)) && !(fl.z & 0x200u) && !m0;
            bool om3 = (((j == (int)(fl.w & 0xffu)) && (fl.w & 0x100u)) || ((i + 3 == bi0) && one0)) && !(fl.w & 0x200u) && !m0;
            float v0 = om0 ? iou_pk(pk.x, my_s, my_e, my_len) : -1.0f;
            float v1 = om1 ? iou_pk(pk.y, my_s, my_e, my_len) : -1.0f;
            float v2 = om2 ? iou_pk(pk.z, my_s, my_e, my_len) : -1.0f;
            float v3 = om3 ? iou_pk(pk.w, my_s, my_e, my_len) : -1.0f;
            if (v0 > best) { best = v0; bi = i; }
            if (v1 > best) { best = v1; bi = i + 1; }
            if (v2 > best) { best = v2; bi = i + 2; }
            if (v3 > best) { best = v3; bi = i + 3; }
        }
        idxc[tid - 128] = bi;
    }
    __syncthreads();

    mm = false;
    if (tid < 128) mm = (idxc[bi] == tid) && (best >= IOU_THRESH);
    else if (tid < 256) mm = (idxr[bi] == tid - 128) && (best >= IOU_THRESH);
    if (tid < 128) {
        ull bb = __ballot(mm);
        if (lane == 0) atomicAdd(&tp_sh, (int)__popcll(bb));
    }
    __syncthreads();

    // ---- 5) per-batch TP/FN/FP with empty-case rules -> per-row slots ----
    if (tid == 0) {
        int n_out = n_out_s, n_tgt = n_tgt_s, tp = tp_sh;
        int tpb, fnb, fpb;
        if (n_tgt == 0)      { tpb = 0;  fnb = n_out;      fpb = 0; }
        else if (n_out == 0) { tpb = 0;  fnb = 0;          fpb = n_tgt; }
        else                 { tpb = tp; fnb = n_tgt - tp; fpb = n_out - tp; }
        per_row[row * 3 + 0] = tpb;
        per_row[row * 3 + 1] = fnb;
        per_row[row * 3 + 2] = fpb;
    }
}

__global__ __launch_bounds__(512) void finalize_kernel(const int* __restrict__ per_row,
                                                       float* __restrict__ out) {
    __shared__ int sm[3][8];
    const int tid = threadIdx.x;
    const int lane = tid & 63;
    const int wid = tid >> 6;
    int tp = per_row[tid * 3 + 0];
    int fn = per_row[tid * 3 + 1];
    int fp = per_row[tid * 3 + 2];
    #pragma unroll
    for (int d = 32; d > 0; d >>= 1) {
        tp += __shfl_down(tp, d, 64);
        fn += __shfl_down(fn, d, 64);
        fp += __shfl_down(fp, d, 64);
    }
    if (lane == 0) { sm[0][wid] = tp; sm[1][wid] = fn; sm[2][wid] = fp; }
    __syncthreads();
    if (tid == 0) {
        int TPi = 0, FNi = 0, FPi = 0;
        #pragma unroll
        for (int w = 0; w < 8; ++w) { TPi += sm[0][w]; FNi += sm[1][w]; FPi += sm[2][w]; }
        float TP = (float)TPi, FN = (float)FNi, FP = (float)FPi;
        float rd = TP + FN;
        float recall = (rd == 0.0f) ? 0.0f : TP / fmaxf(rd, 1.0f);
        float pd = TP + FP;
        float precision = (pd == 0.0f) ? 0.0f : TP / fmaxf(pd, 1.0f);
        float s = precision + recall;
        float f1 = (s == 0.0f) ? 0.0f : 2.0f * precision * recall / fmaxf(s, 1e-30f);
        out[0] = recall; out[1] = precision; out[2] = f1;
    }
}

extern "C" void kernel_launch(void* const* d_in, const int* in_sizes, int n_in,
                              void* d_out, int out_size, void* d_ws, size_t ws_size,
                              hipStream_t stream) {
    const float* outp = (const float*)d_in[0];
    const float* tgtp = (const float*)d_in[1];
    float* res = (float*)d_out;
    int* per_row = (int*)d_ws;

    event_f1_kernel<<<NBATCH, NTHREADS, 0, stream>>>(outp, tgtp, per_row);
    finalize_kernel<<<1, 512, 0, stream>>>(per_row, res);
}